// Round 1
// baseline (408.559 us; speedup 1.0000x reference)
//
#include <hip/hip_runtime.h>
#include <math.h>

#define N_NODES 50000
#define N_EDGES 1600000
#define N_RELS 8
#define N_BASES 4
#define HD 64

// ws layout (floats):
//   c[r][v][3] : (r*N_NODES + v)*3 + k         -> 8*50000*3 = 1,200,000 floats
//   acc[27][64]: ACC_OFF + j*64 + o            -> 1,728 floats
//     j = 3r+0 : u0_r   (sum_v c0[r,v] * F[v,o])
//     j = 3r+1 : u1_r
//     j = 3r+2 : ucnt_r
//     j = 24   : p0[o]   = sum_n f[n,0]*F[n,o]
//     j = 25   : p1[o]   = sum_n f[n,1]*F[n,o]
//     j = 26   : psum[o] = sum_n F[n,o]
#define C_SIZE   (N_RELS * N_NODES * 3)
#define ACC_OFF  C_SIZE
#define ACC_SIZE (27 * HD)
#define WS_FLOATS (C_SIZE + ACC_SIZE)   // 1,201,728 (divisible by 4)

__global__ void zero_ws_kernel(float4* __restrict__ ws) {
    int i = blockIdx.x * blockDim.x + threadIdx.x;
    if (i < WS_FLOATS / 4) ws[i] = make_float4(0.f, 0.f, 0.f, 0.f);
}

__global__ void edge_scatter_kernel(const int* __restrict__ src,
                                    const int* __restrict__ dst,
                                    const int* __restrict__ et,
                                    const float2* __restrict__ feat,
                                    float* __restrict__ c) {
    int e = blockIdx.x * blockDim.x + threadIdx.x;
    if (e >= N_EDGES) return;
    int u = src[e];
    int v = dst[e];
    int r = et[e];
    float2 f = feat[u];   // features[u,0], features[u,1] (8B contiguous)
    float* p = c + ((size_t)r * N_NODES + v) * 3;
    atomicAdd(p + 0, f.x);
    atomicAdd(p + 1, f.y);
    atomicAdd(p + 2, 1.0f);
}

// One 64-lane group per row-stream: lane o owns column o; 27 register
// accumulators per lane; per row, the 24 c-values + 2 features are
// wave-uniform loads (HW broadcast), fcW row load is fully coalesced (256B).
__global__ __launch_bounds__(256) void col_reduce_kernel(
        const float* __restrict__ fcW,
        const float* __restrict__ c,
        const float2* __restrict__ feat,
        float* __restrict__ acc) {
    const int lane = threadIdx.x & 63;
    const int grp  = threadIdx.x >> 6;             // 0..3
    const int gid  = blockIdx.x * 4 + grp;
    const int ngrp = gridDim.x * 4;

    float a[27];
#pragma unroll
    for (int j = 0; j < 27; j++) a[j] = 0.f;

    for (int v = gid; v < N_NODES; v += ngrp) {
        float F  = fcW[v * HD + lane];
        float2 f = feat[v];
#pragma unroll
        for (int r = 0; r < N_RELS; r++) {
            const float* p = c + ((size_t)r * N_NODES + v) * 3;
            a[3 * r + 0] += p[0] * F;
            a[3 * r + 1] += p[1] * F;
            a[3 * r + 2] += p[2] * F;
        }
        a[24] += f.x * F;
        a[25] += f.y * F;
        a[26] += F;
    }

    __shared__ float sm[27 * 256];
#pragma unroll
    for (int j = 0; j < 27; j++) sm[j * 256 + threadIdx.x] = a[j];
    __syncthreads();

    if (threadIdx.x < 64) {
#pragma unroll
        for (int j = 0; j < 27; j++) {
            float s = sm[j * 256 + lane] + sm[j * 256 + 64 + lane] +
                      sm[j * 256 + 128 + lane] + sm[j * 256 + 192 + lane];
            atomicAdd(&acc[j * HD + lane], s);
        }
    }
}

// Single block, 64 lanes; lane o owns output-column o; contracts the 27
// accumulator vectors against bases/w_comp/W_in/b_in/loop_w/h_bias, then
// wave-reduces to the scalar and applies sigmoid.
__global__ void finalize_kernel(const float* __restrict__ W_in,
                                const float* __restrict__ b_in,
                                const float* __restrict__ w_comp,
                                const float* __restrict__ bases,
                                const float* __restrict__ loop_w,
                                const float* __restrict__ h_bias,
                                const float* __restrict__ fc_b,
                                const float* __restrict__ acc,
                                float* __restrict__ out) {
    const int o = threadIdx.x;   // 0..63

    // A0[b][o] = sum_i Win[0,i]*bases[b,i,o]; likewise A1 (Win row 1), Ab (b_in)
    float A0[N_BASES], A1[N_BASES], Ab[N_BASES];
#pragma unroll
    for (int b = 0; b < N_BASES; b++) {
        float s0 = 0.f, s1 = 0.f, sb = 0.f;
        for (int i = 0; i < HD; i++) {
            float bv = bases[(b * HD + i) * HD + o];
            s0 += W_in[i]      * bv;
            s1 += W_in[HD + i] * bv;
            sb += b_in[i]      * bv;
        }
        A0[b] = s0; A1[b] = s1; Ab[b] = sb;
    }

    float partial = 0.f;
#pragma unroll
    for (int r = 0; r < N_RELS; r++) {
        float w0 = 0.f, w1 = 0.f, wb = 0.f;
#pragma unroll
        for (int b = 0; b < N_BASES; b++) {
            float wc = w_comp[r * N_BASES + b];
            w0 += wc * A0[b];
            w1 += wc * A1[b];
            wb += wc * Ab[b];
        }
        partial += w0 * acc[(3 * r + 0) * HD + o]
                 + w1 * acc[(3 * r + 1) * HD + o]
                 + wb * acc[(3 * r + 2) * HD + o];
    }

    // Self-loop: sum_{i,o} loop_w[i,o]*(Win0[i]p0[o] + Win1[i]p1[o] + b_in[i]psum[o])
    float L0 = 0.f, L1 = 0.f, Lb = 0.f;
    for (int i = 0; i < HD; i++) {
        float lw = loop_w[i * HD + o];
        L0 += W_in[i]      * lw;
        L1 += W_in[HD + i] * lw;
        Lb += b_in[i]      * lw;
    }
    partial += L0 * acc[24 * HD + o]
             + L1 * acc[25 * HD + o]
             + (Lb + h_bias[o]) * acc[26 * HD + o];   // h_bias folds into psum term

    // wave reduction over 64 lanes
#pragma unroll
    for (int off = 32; off > 0; off >>= 1)
        partial += __shfl_down(partial, off, 64);

    if (o == 0) {
        float x = partial + fc_b[0];
        out[0] = 1.0f / (1.0f + expf(-x));
    }
}

extern "C" void kernel_launch(void* const* d_in, const int* in_sizes, int n_in,
                              void* d_out, int out_size, void* d_ws, size_t ws_size,
                              hipStream_t stream) {
    const float* features = (const float*)d_in[0];
    const int*   src      = (const int*)d_in[1];
    const int*   dst      = (const int*)d_in[2];
    const int*   etype    = (const int*)d_in[3];
    const float* W_in     = (const float*)d_in[4];
    const float* b_in     = (const float*)d_in[5];
    const float* w_comp   = (const float*)d_in[6];
    const float* bases    = (const float*)d_in[7];
    const float* loop_w   = (const float*)d_in[8];
    const float* h_bias   = (const float*)d_in[9];
    const float* fc_W     = (const float*)d_in[10];
    const float* fc_b     = (const float*)d_in[11];

    float* ws  = (float*)d_ws;
    float* c   = ws;
    float* acc = ws + ACC_OFF;
    float* out = (float*)d_out;

    zero_ws_kernel<<<(WS_FLOATS / 4 + 255) / 256, 256, 0, stream>>>((float4*)d_ws);
    edge_scatter_kernel<<<(N_EDGES + 255) / 256, 256, 0, stream>>>(
        src, dst, etype, (const float2*)features, c);
    col_reduce_kernel<<<160, 256, 0, stream>>>(fc_W, c, (const float2*)features, acc);
    finalize_kernel<<<1, 64, 0, stream>>>(W_in, b_in, w_comp, bases, loop_w,
                                          h_bias, fc_b, acc, out);
}

// Round 2
// 151.219 us; speedup vs baseline: 2.7018x; 2.7018x over previous
//
#include <hip/hip_runtime.h>
#include <math.h>

#define N_NODES 50000
#define N_EDGES 1600000
#define N_RELS 8
#define N_BASES 4
#define HD 64

#define NB_D 196          // ceil(50000/256) blocks in d_table_kernel
#define NB_E 2048         // edge kernel grid (grid-stride)

// ws layout (floats):
//   G[27][64]   at G_OFF    : j=3r+k -> g_{r,k}[o];  j=24,25,26 -> self-loop cols
//   partials    at PART_OFF : [0..NB_D) from d_table_kernel, [NB_D..NB_D+NB_E) from edge kernel
//   D[v][24]    at D_OFF    : per-node scalars, row stride 24 floats (96 B, 16B-aligned)
#define G_OFF    0
#define PART_OFF 1728
#define D_OFF    4096
// total floats = 4096 + 50000*24 = 1,204,096  (= 4.82 MB)

// ---------------------------------------------------------------------------
// Build G[27][64] from bases/w_comp/W_in/b_in/loop_w/h_bias. One 256-thr block.
__global__ void prep_kernel(const float* __restrict__ W_in,
                            const float* __restrict__ b_in,
                            const float* __restrict__ w_comp,
                            const float* __restrict__ bases,
                            const float* __restrict__ loop_w,
                            const float* __restrict__ h_bias,
                            float* __restrict__ G) {
    __shared__ float sA[N_BASES * 3 * HD];   // A[b][k][o]
    const int tid = threadIdx.x;
    const int o = tid & 63;
    const int b = tid >> 6;                  // 0..3

    // Phase 1: A[b][k][o] = sum_i winrow_k[i] * bases[b,i,o]
    {
        float s0 = 0.f, s1 = 0.f, sb = 0.f;
        for (int i = 0; i < HD; i++) {
            float bv = bases[b * HD * HD + i * HD + o];
            s0 += W_in[i]      * bv;
            s1 += W_in[HD + i] * bv;
            sb += b_in[i]      * bv;
        }
        sA[(b * 3 + 0) * HD + o] = s0;
        sA[(b * 3 + 1) * HD + o] = s1;
        sA[(b * 3 + 2) * HD + o] = sb;
    }
    __syncthreads();

    // Phase 2: G[j][o] = sum_b w_comp[r,b] * A[b][k][o],  j = 3r+k
    for (int idx = tid; idx < 24 * HD; idx += 256) {
        int j = idx >> 6, oo = idx & 63;
        int r = j / 3, k = j % 3;
        float s = 0.f;
#pragma unroll
        for (int bb = 0; bb < N_BASES; bb++)
            s += w_comp[r * N_BASES + bb] * sA[(bb * 3 + k) * HD + oo];
        G[j * HD + oo] = s;
    }

    // Phase 3: self-loop columns j=24,25,26
    if (tid < 3 * HD) {
        int k = tid >> 6, oo = tid & 63;
        float s = 0.f;
        for (int i = 0; i < HD; i++) {
            float w = (k == 0) ? W_in[i] : (k == 1) ? W_in[HD + i] : b_in[i];
            s += w * loop_w[i * HD + oo];
        }
        if (k == 2) s += h_bias[oo];
        G[(24 + k) * HD + oo] = s;
    }
}

// ---------------------------------------------------------------------------
// D[v][j] = F[v,:]·G[j,:] for j=0..23; self-loop scalar reduced per block.
// One thread per node; F row held in registers; G read via uniform (scalar) loads.
__global__ __launch_bounds__(256) void d_table_kernel(
        const float4* __restrict__ fcW4,
        const float2* __restrict__ feat,
        const float* __restrict__ G,
        float* __restrict__ D,
        float* __restrict__ partD) {
    const int v = blockIdx.x * 256 + threadIdx.x;
    float part = 0.f;

    if (v < N_NODES) {
        float4 Fr[16];
#pragma unroll
        for (int k = 0; k < 16; k++) Fr[k] = fcW4[v * 16 + k];

        float s[27];
#pragma unroll
        for (int j = 0; j < 27; j++) {
            float acc = 0.f;
#pragma unroll
            for (int k = 0; k < 16; k++) {
                // uniform address -> s_load_dwordx4 (scalar pipe, broadcast)
                float gx = G[j * HD + 4 * k + 0];
                float gy = G[j * HD + 4 * k + 1];
                float gz = G[j * HD + 4 * k + 2];
                float gw = G[j * HD + 4 * k + 3];
                acc += Fr[k].x * gx + Fr[k].y * gy + Fr[k].z * gz + Fr[k].w * gw;
            }
            s[j] = acc;
        }

        float* dp = D + (size_t)v * 24;      // v*96 B, 16B-aligned
#pragma unroll
        for (int j = 0; j < 24; j++) dp[j] = s[j];

        float2 f = feat[v];
        part = s[24] * f.x + s[25] * f.y + s[26];
    }

    __shared__ float red[256];
    red[threadIdx.x] = part;
    __syncthreads();
    for (int st = 128; st > 0; st >>= 1) {
        if (threadIdx.x < st) red[threadIdx.x] += red[threadIdx.x + st];
        __syncthreads();
    }
    if (threadIdx.x == 0) partD[blockIdx.x] = red[0];
}

// ---------------------------------------------------------------------------
// Pure gather over edges: s += f0[u]·D[v,3r] + f1[u]·D[v,3r+1] + D[v,3r+2]
__global__ __launch_bounds__(256) void edge_gather_kernel(
        const int* __restrict__ src,
        const int* __restrict__ dst,
        const int* __restrict__ et,
        const float2* __restrict__ feat,
        const float* __restrict__ D,
        float* __restrict__ partE) {
    float s = 0.f;
    const int stride = NB_E * 256;
    for (int e = blockIdx.x * 256 + threadIdx.x; e < N_EDGES; e += stride) {
        int u = src[e];
        int v = dst[e];
        int r = et[e];
        float2 f = feat[u];
        const float* dp = D + (size_t)v * 24 + r * 3;
        s += f.x * dp[0] + f.y * dp[1] + dp[2];
    }

    __shared__ float red[256];
    red[threadIdx.x] = s;
    __syncthreads();
    for (int st = 128; st > 0; st >>= 1) {
        if (threadIdx.x < st) red[threadIdx.x] += red[threadIdx.x + st];
        __syncthreads();
    }
    if (threadIdx.x == 0) partE[blockIdx.x] = red[0];
}

// ---------------------------------------------------------------------------
__global__ void final_kernel(const float* __restrict__ part,
                             const float* __restrict__ fc_b,
                             float* __restrict__ out) {
    float s = 0.f;
    for (int i = threadIdx.x; i < NB_D + NB_E; i += 256) s += part[i];
    __shared__ float red[256];
    red[threadIdx.x] = s;
    __syncthreads();
    for (int st = 128; st > 0; st >>= 1) {
        if (threadIdx.x < st) red[threadIdx.x] += red[threadIdx.x + st];
        __syncthreads();
    }
    if (threadIdx.x == 0) {
        float x = red[0] + fc_b[0];
        out[0] = 1.0f / (1.0f + expf(-x));
    }
}

extern "C" void kernel_launch(void* const* d_in, const int* in_sizes, int n_in,
                              void* d_out, int out_size, void* d_ws, size_t ws_size,
                              hipStream_t stream) {
    const float* features = (const float*)d_in[0];
    const int*   src      = (const int*)d_in[1];
    const int*   dst      = (const int*)d_in[2];
    const int*   etype    = (const int*)d_in[3];
    const float* W_in     = (const float*)d_in[4];
    const float* b_in     = (const float*)d_in[5];
    const float* w_comp   = (const float*)d_in[6];
    const float* bases    = (const float*)d_in[7];
    const float* loop_w   = (const float*)d_in[8];
    const float* h_bias   = (const float*)d_in[9];
    const float* fc_W     = (const float*)d_in[10];
    const float* fc_b     = (const float*)d_in[11];

    float* ws   = (float*)d_ws;
    float* G    = ws + G_OFF;
    float* part = ws + PART_OFF;      // [0..NB_D) d-partials, [NB_D..NB_D+NB_E) edge
    float* D    = ws + D_OFF;
    float* out  = (float*)d_out;

    prep_kernel<<<1, 256, 0, stream>>>(W_in, b_in, w_comp, bases, loop_w, h_bias, G);
    d_table_kernel<<<NB_D, 256, 0, stream>>>(
        (const float4*)fc_W, (const float2*)features, G, D, part);
    edge_gather_kernel<<<NB_E, 256, 0, stream>>>(
        src, dst, etype, (const float2*)features, D, part + NB_D);
    final_kernel<<<1, 256, 0, stream>>>(part, fc_b, out);
}

// Round 4
// 149.326 us; speedup vs baseline: 2.7360x; 1.0127x over previous
//
#include <hip/hip_runtime.h>
#include <math.h>

#define N_NODES 50000
#define N_EDGES 1600000
#define N_RELS 8
#define N_BASES 4
#define HD 64

#define NB_D 196          // ceil(50000/256) blocks in d_table_kernel
#define NB_E 1024         // edge kernel grid (grid-stride over edge quads)

typedef int   vint4   __attribute__((ext_vector_type(4)));   // native vector: ok for nontemporal builtins

// ws layout (floats):
//   G[27][64]     at G_OFF    : j=3r+k -> g_{r,k}[o]; j=24,25,26 -> self-loop cols
//   partials      at PART_OFF : [0..NB_D) d_table, [NB_D..NB_D+NB_E) edge
//   D[r][v]       at D_OFF    : float4 per (r,v): (d0,d1,d2,0), planar by relation.
//                               float4 index = r*N_NODES + v  -> 400,000 float4s (6.4 MB)
#define G_OFF    0
#define PART_OFF 1728
#define D_OFF    4096

// ---------------------------------------------------------------------------
// Build G[27][64]. One 256-thread block.
__global__ void prep_kernel(const float* __restrict__ W_in,
                            const float* __restrict__ b_in,
                            const float* __restrict__ w_comp,
                            const float* __restrict__ bases,
                            const float* __restrict__ loop_w,
                            const float* __restrict__ h_bias,
                            float* __restrict__ G) {
    __shared__ float sA[N_BASES * 3 * HD];   // A[b][k][o]
    const int tid = threadIdx.x;
    const int o = tid & 63;
    const int b = tid >> 6;                  // 0..3

    // A[b][k][o] = sum_i winrow_k[i] * bases[b,i,o]
    {
        float s0 = 0.f, s1 = 0.f, sb = 0.f;
        for (int i = 0; i < HD; i++) {
            float bv = bases[b * HD * HD + i * HD + o];
            s0 += W_in[i]      * bv;
            s1 += W_in[HD + i] * bv;
            sb += b_in[i]      * bv;
        }
        sA[(b * 3 + 0) * HD + o] = s0;
        sA[(b * 3 + 1) * HD + o] = s1;
        sA[(b * 3 + 2) * HD + o] = sb;
    }
    __syncthreads();

    // G[j][o] = sum_b w_comp[r,b] * A[b][k][o],  j = 3r+k
    for (int idx = tid; idx < 24 * HD; idx += 256) {
        int j = idx >> 6, oo = idx & 63;
        int r = j / 3, k = j % 3;
        float s = 0.f;
#pragma unroll
        for (int bb = 0; bb < N_BASES; bb++)
            s += w_comp[r * N_BASES + bb] * sA[(bb * 3 + k) * HD + oo];
        G[j * HD + oo] = s;
    }

    // self-loop columns j=24,25,26
    if (tid < 3 * HD) {
        int k = tid >> 6, oo = tid & 63;
        float s = 0.f;
        for (int i = 0; i < HD; i++) {
            float w = (k == 0) ? W_in[i] : (k == 1) ? W_in[HD + i] : b_in[i];
            s += w * loop_w[i * HD + oo];
        }
        if (k == 2) s += h_bias[oo];
        G[(24 + k) * HD + oo] = s;
    }
}

// ---------------------------------------------------------------------------
// D[r*N + v] = float4(F[v]·g_{r,0}, F[v]·g_{r,1}, F[v]·g_{r,2}, 0).
// Planar writes -> per-relation stores are fully coalesced dwordx4.
// Self-loop scalar reduced per block into partD.
__global__ __launch_bounds__(256) void d_table_kernel(
        const float4* __restrict__ fcW4,
        const float2* __restrict__ feat,
        const float* __restrict__ G,
        float4* __restrict__ D,
        float* __restrict__ partD) {
    const int v = blockIdx.x * 256 + threadIdx.x;
    float part = 0.f;

    if (v < N_NODES) {
        float4 Fr[16];
#pragma unroll
        for (int k = 0; k < 16; k++) Fr[k] = fcW4[v * 16 + k];

        float s[27];
#pragma unroll
        for (int j = 0; j < 27; j++) {
            float acc = 0.f;
#pragma unroll
            for (int k = 0; k < 16; k++) {
                // uniform addresses -> scalar loads, broadcast
                float gx = G[j * HD + 4 * k + 0];
                float gy = G[j * HD + 4 * k + 1];
                float gz = G[j * HD + 4 * k + 2];
                float gw = G[j * HD + 4 * k + 3];
                acc += Fr[k].x * gx + Fr[k].y * gy + Fr[k].z * gz + Fr[k].w * gw;
            }
            s[j] = acc;
        }

#pragma unroll
        for (int r = 0; r < N_RELS; r++)
            D[r * N_NODES + v] = make_float4(s[3 * r], s[3 * r + 1], s[3 * r + 2], 0.f);

        float2 f = feat[v];
        part = s[24] * f.x + s[25] * f.y + s[26];
    }

    __shared__ float red[256];
    red[threadIdx.x] = part;
    __syncthreads();
    for (int st = 128; st > 0; st >>= 1) {
        if (threadIdx.x < st) red[threadIdx.x] += red[threadIdx.x + st];
        __syncthreads();
    }
    if (threadIdx.x == 0) partD[blockIdx.x] = red[0];
}

// ---------------------------------------------------------------------------
// Pure gather over edges, 4 edges/iteration via vint4 index loads.
// Index streams are nontemporal (one-shot) to keep L2 for D/feat.
__global__ __launch_bounds__(256) void edge_gather_kernel(
        const vint4* __restrict__ src4,
        const vint4* __restrict__ dst4,
        const vint4* __restrict__ et4,
        const float2* __restrict__ feat,
        const float4* __restrict__ D,
        float* __restrict__ partE) {
    const int nquad = N_EDGES / 4;           // 400,000
    const int stride = NB_E * 256;
    float s = 0.f;

    for (int q = blockIdx.x * 256 + threadIdx.x; q < nquad; q += stride) {
        vint4 u = __builtin_nontemporal_load(&src4[q]);
        vint4 v = __builtin_nontemporal_load(&dst4[q]);
        vint4 r = __builtin_nontemporal_load(&et4[q]);

        float2 f0 = feat[u.x];
        float2 f1 = feat[u.y];
        float2 f2 = feat[u.z];
        float2 f3 = feat[u.w];
        float4 d0 = D[r.x * N_NODES + v.x];
        float4 d1 = D[r.y * N_NODES + v.y];
        float4 d2 = D[r.z * N_NODES + v.z];
        float4 d3 = D[r.w * N_NODES + v.w];

        s += f0.x * d0.x + f0.y * d0.y + d0.z;
        s += f1.x * d1.x + f1.y * d1.y + d1.z;
        s += f2.x * d2.x + f2.y * d2.y + d2.z;
        s += f3.x * d3.x + f3.y * d3.y + d3.z;
    }

    __shared__ float red[256];
    red[threadIdx.x] = s;
    __syncthreads();
    for (int st = 128; st > 0; st >>= 1) {
        if (threadIdx.x < st) red[threadIdx.x] += red[threadIdx.x + st];
        __syncthreads();
    }
    if (threadIdx.x == 0) partE[blockIdx.x] = red[0];
}

// ---------------------------------------------------------------------------
__global__ void final_kernel(const float* __restrict__ part,
                             const float* __restrict__ fc_b,
                             float* __restrict__ out) {
    float s = 0.f;
    for (int i = threadIdx.x; i < NB_D + NB_E; i += 256) s += part[i];
    __shared__ float red[256];
    red[threadIdx.x] = s;
    __syncthreads();
    for (int st = 128; st > 0; st >>= 1) {
        if (threadIdx.x < st) red[threadIdx.x] += red[threadIdx.x + st];
        __syncthreads();
    }
    if (threadIdx.x == 0) {
        float x = red[0] + fc_b[0];
        out[0] = 1.0f / (1.0f + expf(-x));
    }
}

extern "C" void kernel_launch(void* const* d_in, const int* in_sizes, int n_in,
                              void* d_out, int out_size, void* d_ws, size_t ws_size,
                              hipStream_t stream) {
    const float* features = (const float*)d_in[0];
    const int*   src      = (const int*)d_in[1];
    const int*   dst      = (const int*)d_in[2];
    const int*   etype    = (const int*)d_in[3];
    const float* W_in     = (const float*)d_in[4];
    const float* b_in     = (const float*)d_in[5];
    const float* w_comp   = (const float*)d_in[6];
    const float* bases    = (const float*)d_in[7];
    const float* loop_w   = (const float*)d_in[8];
    const float* h_bias   = (const float*)d_in[9];
    const float* fc_W     = (const float*)d_in[10];
    const float* fc_b     = (const float*)d_in[11];

    float* ws   = (float*)d_ws;
    float* G    = ws + G_OFF;
    float* part = ws + PART_OFF;
    float4* D   = (float4*)(ws + D_OFF);
    float* out  = (float*)d_out;

    prep_kernel<<<1, 256, 0, stream>>>(W_in, b_in, w_comp, bases, loop_w, h_bias, G);
    d_table_kernel<<<NB_D, 256, 0, stream>>>(
        (const float4*)fc_W, (const float2*)features, G, D, part);
    edge_gather_kernel<<<NB_E, 256, 0, stream>>>(
        (const vint4*)src, (const vint4*)dst, (const vint4*)etype,
        (const float2*)features, D, part + NB_D);
    final_kernel<<<1, 256, 0, stream>>>(part, fc_b, out);
}